// Round 4
// baseline (629.357 us; speedup 1.0000x reference)
//
#include <hip/hip_runtime.h>
#include <hip/hip_bf16.h>

// Problem constants
#define EDIM 1024
#define HHEADS 16
#define DHEAD 64
#define BB 4
#define NSEQ 4096
#define NTOK 16384   // BB*NSEQ
#define KVSPLIT 16

typedef unsigned short u16;
using frag8 = __attribute__((ext_vector_type(8))) short;   // 8 bf16 (4 VGPRs)
using facc4 = __attribute__((ext_vector_type(4))) float;   // 4 f32 acc

__device__ __forceinline__ float b2f(u16 u) {
  union { unsigned int i; float f; } c; c.i = ((unsigned int)u) << 16; return c.f;
}
__device__ __forceinline__ u16 f2b(float f) {
  __hip_bfloat16 h = __float2bfloat16(f);   // RNE
  union { __hip_bfloat16 h; u16 u; } c; c.h = h; return c.u;
}
__device__ __forceinline__ void gl2lds16(const void* g, void* l) {
  __builtin_amdgcn_global_load_lds(
      (const __attribute__((address_space(1))) unsigned int*)g,
      (__attribute__((address_space(3))) unsigned int*)l, 16, 0, 0);
}

// ---------------------------------------------------------------------------
// Dtype probe: flag[0]=1 -> inputs are bf16, 0 -> f32 (per reference).
// ---------------------------------------------------------------------------
__global__ void detect_dtype(const u16* __restrict__ src, unsigned* __restrict__ flag) {
  const int lane = threadIdx.x;                    // 64 threads
  const unsigned u = src[(size_t)lane * 200000];   // even u16 indices
  const unsigned e = (u >> 7) & 0xFF;
  const bool inl = (u == 0) || (e >= 100 && e <= 135);
  const unsigned long long m = __ballot(inl);
  if (lane == 0) flag[0] = (__popcll(m) >= 32) ? 1u : 0u;
}

// ---------------------------------------------------------------------------
// Single weight/vector conversion kernel (f32 world only; no-op in bf16).
// Blocks 0..2047: 4 weights (512 blocks each, 1M elems). Blocks 2048..2051:
// 8 vectors of 1024.
// ---------------------------------------------------------------------------
struct WCvtArgs { const void* s[12]; u16* d[12]; };
__global__ __launch_bounds__(256) void wcvt(WCvtArgs p, const unsigned* __restrict__ flag) {
  if (flag[0] == 1) return;
  const float* src;
  u16* dst;
  size_t idx;
  if (blockIdx.x < 2048) {
    const int wsel = blockIdx.x >> 9;
    idx = (size_t)(((blockIdx.x & 511) * 256 + threadIdx.x)) * 8;
    src = (const float*)p.s[wsel];
    dst = p.d[wsel];
  } else {
    const int t2 = (blockIdx.x - 2048) * 256 + threadIdx.x;  // 0..1023
    const int vsel = 4 + (t2 >> 7);
    idx = (size_t)(t2 & 127) * 8;
    src = (const float*)p.s[vsel];
    dst = p.d[vsel];
  }
  const float4 a = *(const float4*)(src + idx);
  const float4 b = *(const float4*)(src + idx + 4);
  union { u16 us[8]; uint4 v; } pk;
  pk.us[0] = f2b(a.x); pk.us[1] = f2b(a.y); pk.us[2] = f2b(a.z); pk.us[3] = f2b(a.w);
  pk.us[4] = f2b(b.x); pk.us[5] = f2b(b.y); pk.us[6] = f2b(b.z); pk.us[7] = f2b(b.w);
  *(uint4*)(dst + idx) = pk.v;
}

// ---------------------------------------------------------------------------
// GEMM: C[M,1024] = A[M,1024] @ W[1024,1024]^T + bias (bf16 MFMA, f32 acc).
// BK=64 via dual 32-wide LDS stages (halves barrier count vs BK=32).
// aMode=0: Araw is always bf16. aMode=1: Araw is bf16 or f32 per flag; in the
// f32 world A is converted in-staging (float4 load -> bf16 -> ds_write_b128).
// outMode=1: f32 C store in the f32 world.
// ---------------------------------------------------------------------------
__global__ __launch_bounds__(256, 2) void gemm_bias(
    const void* __restrict__ Araw, const void* __restrict__ Wraw,
    const u16* __restrict__ Wcvt, const void* __restrict__ biasRaw,
    const u16* __restrict__ biasCvt, u16* __restrict__ C,
    const unsigned* __restrict__ flag, int aMode, int outMode)
{
  __shared__ __align__(16) u16 As0[4096];   // [128][32] each, pitch 64B
  __shared__ __align__(16) u16 As1[4096];
  __shared__ __align__(16) u16 Bs0[4096];
  __shared__ __align__(16) u16 Bs1[4096];
  const int tid  = threadIdx.x;
  const int lane = tid & 63;
  const int w    = tid >> 6;
  const int wm   = w >> 1, wn = w & 1;
  const int rowBase = blockIdx.x * 128;
  const int colBase = blockIdx.y * 128;

  const bool bfw = (flag[0] == 1);
  const u16* W    = bfw ? (const u16*)Wraw    : Wcvt;
  const u16* bias = bfw ? (const u16*)biasRaw : biasCvt;
  const bool aBf  = bfw || (aMode == 0);

  facc4 acc[4][4];
#pragma unroll
  for (int i = 0; i < 4; ++i)
#pragma unroll
    for (int j = 0; j < 4; ++j) acc[i][j] = (facc4){0.f, 0.f, 0.f, 0.f};

  // staging constants (bf16 path): wave w covers tile rows [w*32, w*32+32)
  const int sRow = w * 32 + (lane >> 2);
  const int sCol = (lane & 3) * 8;
  const u16* Wg = W + (size_t)(colBase + sRow) * EDIM + sCol;
  u16* AsB0 = As0 + w * 1024;
  u16* AsB1 = As1 + w * 1024;
  u16* BsB0 = Bs0 + w * 1024;
  u16* BsB1 = Bs1 + w * 1024;

  const int fr = lane & 15;
  const int kq = (lane >> 4) * 8;

  if (aBf) {
    const u16* Ag = (const u16*)Araw + (size_t)(rowBase + sRow) * EDIM + sCol;
    for (int k0 = 0; k0 < EDIM; k0 += 64) {
      gl2lds16(Ag + k0,                 AsB0);
      gl2lds16(Ag + k0 + 16 * EDIM,      AsB0 + 512);
      gl2lds16(Ag + k0 + 32,             AsB1);
      gl2lds16(Ag + k0 + 32 + 16 * EDIM, AsB1 + 512);
      gl2lds16(Wg + k0,                 BsB0);
      gl2lds16(Wg + k0 + 16 * EDIM,      BsB0 + 512);
      gl2lds16(Wg + k0 + 32,             BsB1);
      gl2lds16(Wg + k0 + 32 + 16 * EDIM, BsB1 + 512);
      __syncthreads();
#pragma unroll
      for (int s = 0; s < 2; ++s) {
        const u16* Ah = s ? As1 : As0;
        const u16* Bh = s ? Bs1 : Bs0;
        frag8 af[4], bf[4];
#pragma unroll
        for (int i = 0; i < 4; ++i)
          af[i] = *(const frag8*)(Ah + (wm * 64 + i * 16 + fr) * 32 + kq);
#pragma unroll
        for (int j = 0; j < 4; ++j)
          bf[j] = *(const frag8*)(Bh + (wn * 64 + j * 16 + fr) * 32 + kq);
#pragma unroll
        for (int i = 0; i < 4; ++i)
#pragma unroll
          for (int j = 0; j < 4; ++j)
            acc[i][j] = __builtin_amdgcn_mfma_f32_16x16x32_bf16(af[i], bf[j], acc[i][j], 0, 0, 0);
      }
      __syncthreads();
    }
  } else {
    // f32-world A: manual staged conversion
    const float* Af = (const float*)Araw;
    const int frow = w * 32 + (lane >> 3);     // +g*8
    const int fcol = (lane & 7) * 8;           // 0..56
    u16* dhalf = (fcol < 32) ? As0 : As1;
    const int dcol = fcol & 31;
    for (int k0 = 0; k0 < EDIM; k0 += 64) {
#pragma unroll
      for (int g = 0; g < 4; ++g) {
        const int r = frow + g * 8;
        const float* src = Af + (size_t)(rowBase + r) * EDIM + k0 + fcol;
        const float4 x0 = *(const float4*)src;
        const float4 x1 = *(const float4*)(src + 4);
        union { u16 us[8]; uint4 v; } pk;
        pk.us[0] = f2b(x0.x); pk.us[1] = f2b(x0.y); pk.us[2] = f2b(x0.z); pk.us[3] = f2b(x0.w);
        pk.us[4] = f2b(x1.x); pk.us[5] = f2b(x1.y); pk.us[6] = f2b(x1.z); pk.us[7] = f2b(x1.w);
        *(uint4*)(dhalf + (size_t)r * 32 + dcol) = pk.v;
      }
      gl2lds16(Wg + k0,                 BsB0);
      gl2lds16(Wg + k0 + 16 * EDIM,      BsB0 + 512);
      gl2lds16(Wg + k0 + 32,             BsB1);
      gl2lds16(Wg + k0 + 32 + 16 * EDIM, BsB1 + 512);
      __syncthreads();
#pragma unroll
      for (int s = 0; s < 2; ++s) {
        const u16* Ah = s ? As1 : As0;
        const u16* Bh = s ? Bs1 : Bs0;
        frag8 af[4], bf[4];
#pragma unroll
        for (int i = 0; i < 4; ++i)
          af[i] = *(const frag8*)(Ah + (wm * 64 + i * 16 + fr) * 32 + kq);
#pragma unroll
        for (int j = 0; j < 4; ++j)
          bf[j] = *(const frag8*)(Bh + (wn * 64 + j * 16 + fr) * 32 + kq);
#pragma unroll
        for (int i = 0; i < 4; ++i)
#pragma unroll
          for (int j = 0; j < 4; ++j)
            acc[i][j] = __builtin_amdgcn_mfma_f32_16x16x32_bf16(af[i], bf[j], acc[i][j], 0, 0, 0);
      }
      __syncthreads();
    }
  }

  const bool f32out = (outMode == 1) && !bfw;
  float* Cf = (float*)C;
  float bvv[4];
#pragma unroll
  for (int j = 0; j < 4; ++j)
    bvv[j] = b2f(bias[colBase + wn * 64 + j * 16 + fr]);
#pragma unroll
  for (int i = 0; i < 4; ++i) {
#pragma unroll
    for (int r = 0; r < 4; ++r) {
      const int row = rowBase + wm * 64 + i * 16 + (lane >> 4) * 4 + r;  // C/D: row=quad*4+reg
      const size_t ro = (size_t)row * EDIM + colBase + wn * 64 + fr;     // col=lane&15
#pragma unroll
      for (int j = 0; j < 4; ++j) {
        const float val = acc[i][j][r] + bvv[j];
        if (f32out) Cf[ro + j * 16] = val;
        else        C[ro + j * 16]  = f2b(val);
      }
    }
  }
}

// ---------------------------------------------------------------------------
// Fused LayerNorm (+g,beta) then elu+1 for Q and K in one dispatch.
// Grid 2*NTOK: blocks [0,NTOK) -> Q rows, [NTOK,2*NTOK) -> K rows. In-place.
// ---------------------------------------------------------------------------
__global__ __launch_bounds__(256) void ln_elu2(
    u16* __restrict__ Xq, u16* __restrict__ Xk,
    const void* __restrict__ gqRaw, const u16* __restrict__ gqCvt,
    const void* __restrict__ bqRaw, const u16* __restrict__ bqCvt,
    const void* __restrict__ gkRaw, const u16* __restrict__ gkCvt,
    const void* __restrict__ bkRaw, const u16* __restrict__ bkCvt,
    const unsigned* __restrict__ flag)
{
  __shared__ float wsum[4], wsq[4];
  const bool bfw = (flag[0] == 1);
  const bool isK = blockIdx.x >= NTOK;
  const int row  = isK ? (blockIdx.x - NTOK) : blockIdx.x;
  u16* X = isK ? Xk : Xq;
  const u16* g    = isK ? (bfw ? (const u16*)gkRaw : gkCvt)
                        : (bfw ? (const u16*)gqRaw : gqCvt);
  const u16* beta = isK ? (bfw ? (const u16*)bkRaw : bkCvt)
                        : (bfw ? (const u16*)bqRaw : bqCvt);
  const int tid = threadIdx.x;
  const ushort4 xu = ((const ushort4*)(X + (size_t)row * EDIM))[tid];
  float x[4] = { b2f(xu.x), b2f(xu.y), b2f(xu.z), b2f(xu.w) };
  float s  = x[0] + x[1] + x[2] + x[3];
  float ss = x[0]*x[0] + x[1]*x[1] + x[2]*x[2] + x[3]*x[3];
#pragma unroll
  for (int off = 32; off > 0; off >>= 1) {
    s  += __shfl_down(s,  off, 64);
    ss += __shfl_down(ss, off, 64);
  }
  if ((tid & 63) == 0) { wsum[tid >> 6] = s; wsq[tid >> 6] = ss; }
  __syncthreads();
  const float S  = wsum[0] + wsum[1] + wsum[2] + wsum[3];
  const float SS = wsq[0] + wsq[1] + wsq[2] + wsq[3];
  const float mu  = S * (1.0f / EDIM);
  const float var = SS * (1.0f / EDIM) - mu * mu;
  const float rs  = rsqrtf(var + 1e-5f);
  const ushort4 gu = ((const ushort4*)g)[tid];
  const ushort4 bu = ((const ushort4*)beta)[tid];
  float gg[4] = { b2f(gu.x), b2f(gu.y), b2f(gu.z), b2f(gu.w) };
  float bb[4] = { b2f(bu.x), b2f(bu.y), b2f(bu.z), b2f(bu.w) };
  ushort4 out;
  u16 o[4];
#pragma unroll
  for (int c = 0; c < 4; ++c) {
    float y = (x[c] - mu) * rs * gg[c] + bb[c];
    y = (y > 0.f) ? (y + 1.f) : __expf(y);   // elu(y)+1
    o[c] = f2b(y);
  }
  out.x = o[0]; out.y = o[1]; out.z = o[2]; out.w = o[3];
  ((ushort4*)(X + (size_t)row * EDIM))[tid] = out;
}

// ---------------------------------------------------------------------------
// Stage 1: per-(split,h,b) partial kv_sum (64x64 f32) + partial k_sum -> own
// global slots (NO atomics). 256 n per block, 2 chunks of 128.
// ---------------------------------------------------------------------------
__global__ __launch_bounds__(256) void kv_partial(
    const u16* __restrict__ Km, const u16* __restrict__ V,
    float* __restrict__ partials, float* __restrict__ kspart)
{
  __shared__ __align__(16) u16 smem[2 * 64 * 130];   // kT | vT, 33.3 KB
  u16 (*kT)[130] = (u16(*)[130])smem;
  u16 (*vT)[130] = (u16(*)[130])(smem + 64 * 130);
  float* red = (float*)smem;            // pitch 68; reused after MFMA
  float* ksr = ((float*)smem) + 4352;   // 4 waves x 64 floats

  const int split = blockIdx.x, h = blockIdx.y, b = blockIdx.z;
  const int bh = b * HHEADS + h;
  const int tid = threadIdx.x, lane = tid & 63, w = tid >> 6;
  const size_t base = (size_t)b * NSEQ * EDIM + h * DHEAD;
  const int nbase = split * (NSEQ / KVSPLIT);   // 256 n per block

  float ksacc[8] = {0, 0, 0, 0, 0, 0, 0, 0};
  facc4 acc[4][4];
#pragma unroll
  for (int i = 0; i < 4; ++i)
#pragma unroll
    for (int j = 0; j < 4; ++j) acc[i][j] = (facc4){0.f, 0.f, 0.f, 0.f};

  const int e0 = (tid & 7) * 8;
  const int nl0 = tid >> 3;      // 0..31
  const int fr = lane & 15;
  const int quad = lane >> 4;

  for (int c = 0; c < 2; ++c) {
    const int nchunk = nbase + c * 128;
#pragma unroll
    for (int rep = 0; rep < 4; ++rep) {
      const int n = rep * 32 + nl0;
      const uint4 kd = *(const uint4*)(Km + base + (size_t)(nchunk + n) * EDIM + e0);
      const uint4 vd = *(const uint4*)(V  + base + (size_t)(nchunk + n) * EDIM + e0);
      const u16* pk = (const u16*)&kd;
      const u16* pv = (const u16*)&vd;
#pragma unroll
      for (int ii = 0; ii < 8; ++ii) {
        kT[e0 + ii][n] = pk[ii];
        ksacc[ii] += b2f(pk[ii]);
        vT[e0 + ii][n] = pv[ii];
      }
    }
    __syncthreads();
    const int kq2 = w * 32 + quad * 8;   // wave w contracts n in [w*32,(w+1)*32)
    frag8 af[4], bf[4];
#pragma unroll
    for (int i = 0; i < 4; ++i) af[i] = *(const frag8*)&kT[i * 16 + fr][kq2];
#pragma unroll
    for (int j = 0; j < 4; ++j) bf[j] = *(const frag8*)&vT[j * 16 + fr][kq2];
#pragma unroll
    for (int i = 0; i < 4; ++i)
#pragma unroll
      for (int j = 0; j < 4; ++j)
        acc[i][j] = __builtin_amdgcn_mfma_f32_16x16x32_bf16(af[i], bf[j], acc[i][j], 0, 0, 0);
    __syncthreads();
  }

  // rotated cross-wave reduction into red (pitch 68)
  for (int p = 0; p < 4; ++p) {
    const int j = (w + p) & 3;
#pragma unroll
    for (int i = 0; i < 4; ++i)
#pragma unroll
      for (int r = 0; r < 4; ++r) {
        const int d = i * 16 + quad * 4 + r;
        const int e = j * 16 + fr;
        if (p == 0) red[d * 68 + e] = acc[i][j][r];
        else        red[d * 68 + e] += acc[i][j][r];
      }
    __syncthreads();
  }

  const size_t pbase = ((size_t)bh * KVSPLIT + split) * 4096;
#pragma unroll
  for (int ii = 0; ii < 16; ++ii) {
    const int idx = tid + ii * 256;
    partials[pbase + idx] = red[(idx >> 6) * 68 + (idx & 63)];
  }

#pragma unroll
  for (int ii = 0; ii < 8; ++ii) {
    ksacc[ii] += __shfl_down(ksacc[ii], 32, 64);
    ksacc[ii] += __shfl_down(ksacc[ii], 16, 64);
    ksacc[ii] += __shfl_down(ksacc[ii], 8, 64);
  }
  if (lane < 8) {
#pragma unroll
    for (int ii = 0; ii < 8; ++ii) ksr[w * 64 + lane * 8 + ii] = ksacc[ii];
  }
  __syncthreads();
  if (tid < 64)
    kspart[((size_t)bh * KVSPLIT + split) * 64 + tid] =
        ksr[tid] + ksr[64 + tid] + ksr[128 + tid] + ksr[192 + tid];
}

// Stage 2: reduce KVSPLIT partial slots -> KV f32 [d][e] and Ks.
__global__ __launch_bounds__(256) void kv_reduce(
    const float* __restrict__ partials, const float* __restrict__ kspart,
    float* __restrict__ KV, float* __restrict__ Ks)
{
  const int qt = blockIdx.x;   // 0..3
  const int bh = blockIdx.y;   // 0..63
  const int tid = threadIdx.x;
#pragma unroll
  for (int ii = 0; ii < 4; ++ii) {
    const int idx = qt * 1024 + ii * 256 + tid;
    float s = 0.f;
#pragma unroll
    for (int sp = 0; sp < KVSPLIT; ++sp)
      s += partials[((size_t)bh * KVSPLIT + sp) * 4096 + idx];
    KV[(size_t)bh * 4096 + idx] = s;
  }
  if (qt == 0 && tid < 64) {
    float s = 0.f;
#pragma unroll
    for (int sp = 0; sp < KVSPLIT; ++sp)
      s += kspart[((size_t)bh * KVSPLIT + sp) * 64 + tid];
    Ks[bh * 64 + tid] = s;
  }
}

// ---------------------------------------------------------------------------
// attn[b,q,h,e] = (sum_d q[b,q,h,d]*kv[bh][d][e]) / (q . ksum[bh] + 1e-8)
// ---------------------------------------------------------------------------
__global__ __launch_bounds__(256) void attn_nd(
    const u16* __restrict__ Q, const float* __restrict__ KV,
    const float* __restrict__ Ks, u16* __restrict__ O)
{
  __shared__ __align__(16) u16 kvT[64][72];  // [e][d], pad +8
  __shared__ float ks_s[64];
  __shared__ float den_s[4][16];
  const int qt = blockIdx.x, h = blockIdx.y, b = blockIdx.z;
  const int bh = b * HHEADS + h;
  const int tid = threadIdx.x, lane = tid & 63, w = tid >> 6;
  const float* kvp = KV + (size_t)bh * 4096;
#pragma unroll
  for (int ii = 0; ii < 16; ++ii) {
    const int idx = tid + ii * 256;          // idx = d*64+e
    kvT[idx & 63][idx >> 6] = f2b(kvp[idx]);
  }
  if (tid < 64) ks_s[tid] = Ks[bh * 64 + tid];
  __syncthreads();

  const int fr = lane & 15;
  const int q8 = (lane >> 4) * 8;
  const u16* qp = Q + (size_t)(b * NSEQ + qt * 64 + w * 16 + fr) * EDIM + h * DHEAD;
  const frag8 a0 = *(const frag8*)(qp + q8);
  const frag8 a1 = *(const frag8*)(qp + 32 + q8);

  const u16* a0u = (const u16*)&a0;
  const u16* a1u = (const u16*)&a1;
  float den = 0.f;
#pragma unroll
  for (int j = 0; j < 8; ++j)
    den += b2f(a0u[j]) * ks_s[q8 + j] + b2f(a1u[j]) * ks_s[32 + q8 + j];
  den += __shfl_xor(den, 16, 64);
  den += __shfl_xor(den, 32, 64);
  if (lane < 16) den_s[w][lane] = den + 1e-8f;

  facc4 acc[4];
#pragma unroll
  for (int j = 0; j < 4; ++j) acc[j] = (facc4){0.f, 0.f, 0.f, 0.f};
#pragma unroll
  for (int j = 0; j < 4; ++j) {
    const frag8 b0 = *(const frag8*)&kvT[j * 16 + fr][q8];
    const frag8 b1 = *(const frag8*)&kvT[j * 16 + fr][32 + q8];
    acc[j] = __builtin_amdgcn_mfma_f32_16x16x32_bf16(a0, b0, acc[j], 0, 0, 0);
    acc[j] = __builtin_amdgcn_mfma_f32_16x16x32_bf16(a1, b1, acc[j], 0, 0, 0);
  }
  __syncthreads();
#pragma unroll
  for (int r = 0; r < 4; ++r) {
    const int rq = (lane >> 4) * 4 + r;
    const float dv = den_s[w][rq];
    const size_t orow = (size_t)(b * NSEQ + qt * 64 + w * 16 + rq) * EDIM + h * DHEAD;
#pragma unroll
    for (int j = 0; j < 4; ++j)
      O[orow + j * 16 + fr] = f2b(acc[j][r] / dv);
  }
}

// ---------------------------------------------------------------------------
extern "C" void kernel_launch(void* const* d_in, const int* in_sizes, int n_in,
                              void* d_out, int out_size, void* d_ws, size_t ws_size,
                              hipStream_t stream) {
  char* ws = (char*)d_ws;
  const size_t EH = (size_t)NTOK * EDIM;      // 16.78M elems
  unsigned* flag = (unsigned*)ws;             // 1 KB slot
  u16* Wqb  = (u16*)(ws + 1024);
  u16* Wkb  = Wqb + EDIM * EDIM;
  u16* Wvb  = Wkb + EDIM * EDIM;
  u16* Wob  = Wvb + EDIM * EDIM;
  u16* bqb  = Wob + EDIM * EDIM;
  u16* bkb  = bqb + 1024;
  u16* bvb  = bkb + 1024;
  u16* bob  = bvb + 1024;
  u16* gqb  = bob + 1024;
  u16* bEqb = gqb + 1024;
  u16* gkb  = bEqb + 1024;
  u16* bEkb = gkb + 1024;
  u16* Xin  = bEkb + 1024;    // attn output staging (always bf16)
  u16* preQ = Xin + EH;
  u16* preK = preQ + EH;
  u16* vbuf = preK + EH;
  float* partials = (float*)(vbuf + EH);              // 64*16*4096 f32 = 16.8MB
  float* kspart   = partials + (size_t)64 * KVSPLIT * 4096;
  float* kvbuf    = kspart + (size_t)64 * KVSPLIT * 64;
  float* ksbuf    = kvbuf + (size_t)64 * 4096;

  const dim3 gg(NTOK / 128, EDIM / 128), tb(256);

  detect_dtype<<<1, 64, 0, stream>>>((const u16*)d_in[0], flag);

  WCvtArgs wa;
  wa.s[0] = d_in[3];  wa.s[1] = d_in[5];  wa.s[2] = d_in[7];  wa.s[3] = d_in[9];
  wa.s[4] = d_in[4];  wa.s[5] = d_in[6];  wa.s[6] = d_in[8];  wa.s[7] = d_in[10];
  wa.s[8] = d_in[11]; wa.s[9] = d_in[12]; wa.s[10] = d_in[13]; wa.s[11] = d_in[14];
  wa.d[0] = Wqb; wa.d[1] = Wkb; wa.d[2] = Wvb; wa.d[3] = Wob;
  wa.d[4] = bqb; wa.d[5] = bkb; wa.d[6] = bvb; wa.d[7] = bob;
  wa.d[8] = gqb; wa.d[9] = bEqb; wa.d[10] = gkb; wa.d[11] = bEkb;
  wcvt<<<2052, 256, 0, stream>>>(wa, flag);

  gemm_bias<<<gg, tb, 0, stream>>>(d_in[0], d_in[3], Wqb, d_in[4],  bqb, preQ, flag, 1, 0);
  gemm_bias<<<gg, tb, 0, stream>>>(d_in[1], d_in[5], Wkb, d_in[6],  bkb, preK, flag, 1, 0);
  gemm_bias<<<gg, tb, 0, stream>>>(d_in[2], d_in[7], Wvb, d_in[8],  bvb, vbuf, flag, 1, 0);

  ln_elu2<<<2 * NTOK, 256, 0, stream>>>(preQ, preK,
      d_in[11], gqb, d_in[12], bEqb, d_in[13], gkb, d_in[14], bEkb, flag);

  kv_partial<<<dim3(KVSPLIT, HHEADS, BB), tb, 0, stream>>>(preK, vbuf, partials, kspart);
  kv_reduce<<<dim3(4, 64), tb, 0, stream>>>(partials, kspart, kvbuf, ksbuf);
  attn_nd<<<dim3(NSEQ / 64, HHEADS, BB), tb, 0, stream>>>(preQ, kvbuf, ksbuf, Xin);

  gemm_bias<<<gg, tb, 0, stream>>>(Xin, d_in[9], Wob, d_in[10], bob, (u16*)d_out, flag, 0, 1);
}